// Round 10
// baseline (476.571 us; speedup 1.0000x reference)
//
#include <hip/hip_runtime.h>
#include <cstdint>
#include <cstddef>

// ---- problem constants ----
#define B_      2
#define S_      2048
#define DIM_    2048
#define H_      16
#define KV_LORA_ 512
#define NOPE_D_ 128
#define ROPE_D_ 64
#define V_D_    128
#define Q_D_    192          // NOPE_D + ROPE_D
#define EPS_    1e-6f
#define BS_     (B_ * S_)    // 4096 rows
#define CKV_P_  768          // ckv row pitch (576 real cols, padded to 768)

typedef __attribute__((ext_vector_type(8))) short bf16x8;
typedef __attribute__((ext_vector_type(4))) float f32x4;
typedef __attribute__((ext_vector_type(16))) float f32x16;

__device__ __forceinline__ ushort f2bf(float f) {
    union { float f; uint32_t u; } v; v.f = f;
    uint32_t u = v.u + 0x7fff + ((v.u >> 16) & 1);  // RNE
    return (ushort)(u >> 16);
}
__device__ __forceinline__ float bf2f(ushort u) {
    union { uint32_t u; float f; } v; v.u = (uint32_t)u << 16; return v.f;
}
__device__ __forceinline__ void gll16(const void* g, void* l) {
    __builtin_amdgcn_global_load_lds(
        (const __attribute__((address_space(1))) unsigned int*)g,
        (__attribute__((address_space(3))) unsigned int*)l, 16, 0, 0);
}

#define GQ_BARRIER()  __builtin_amdgcn_s_barrier()
#define GQ_LGKM0()    do { asm volatile("s_waitcnt lgkmcnt(0)" ::: "memory"); \
                           __builtin_amdgcn_sched_barrier(0); } while (0)

// ============================================================================
// 256x256 8-phase bf16 GEMM (round-8 coalesced+swizzled staging, proven).
// MODE: 0 = f32 pitch N, 1 = bf16 pitch N,
//       2 = split (q-proj bf16 pitch 3072 | ckv f32 pitch 768),
//       3 = kvb + fused V-transpose.
// ============================================================================
template <int MODE>
__global__ __launch_bounds__(512, 2) void gemm256_8ph(
    const ushort* __restrict__ A, const ushort* __restrict__ Bw,
    void* __restrict__ Cv, void* __restrict__ Cv2, int N, int K, int nbx)
{
    __shared__ __align__(16) ushort L[2][2][2][8192];   // 128 KB (slot=16KB)

    const int tid = threadIdx.x;
    const int lane = tid & 63;
    const int w = tid >> 6;
    const int l15 = lane & 15, quad = lane >> 4;
    const int q8 = quad * 8;
    const int rsw8 = ((l15 >> 1) & 3) * 8;    // read-side XOR term (ushorts)

    const int nwg = (int)gridDim.x;
    const int cpx = nwg >> 3;
    const int lin = (int)blockIdx.x;
    const int swz = (lin & 7) * cpx + (lin >> 3);
    const int m0 = (swz / nbx) * 256;
    const int n0 = (swz % nbx) * 256;

    const int wm0 = (w & 3) * 64;
    const int wn0 = (w >> 2) * 128;

    const int NT = K >> 6;

    f32x4 acc[4][8];
#pragma unroll
    for (int i = 0; i < 4; ++i)
#pragma unroll
        for (int j = 0; j < 8; ++j) acc[i][j] = (f32x4){0.f, 0.f, 0.f, 0.f};

    const int srow = lane >> 2;                        // row within 16-row chunk
    const int scg  = (lane & 3) ^ ((lane >> 3) & 3);   // permuted col-group

    auto stage = [&](int ab, int kh, int kt, int buf) {
#pragma unroll
        for (int j = 0; j < 2; ++j) {
            int ci = w + j * 8;
            ushort* dst = &L[buf][ab][kh][ci * 512 + lane * 8];
            int row = ci * 16 + srow;
            const ushort* src = (ab ? Bw + (size_t)(n0 + row) * K
                                    : A  + (size_t)(m0 + row) * K)
                                + kt * 64 + kh * 32 + scg * 8;
            gll16(src, dst);
        }
    };

    // ---- prologue ----
    stage(0, 0, 0, 0); stage(1, 0, 0, 0); stage(0, 1, 0, 0); stage(1, 1, 0, 0);
    if (NT > 1) { stage(0, 0, 1, 1); stage(1, 0, 1, 1); stage(0, 1, 1, 1); }
    else        { stage(0, 0, 0, 1); stage(1, 0, 0, 1); stage(0, 1, 0, 1); }
    asm volatile("s_waitcnt vmcnt(6)" ::: "memory");
    GQ_BARRIER();

    bf16x8 a[4], b[4];

    for (int t = 0; t < NT; ++t) {
        const int c = t & 1, o = c ^ 1;
        const int kt1 = (t + 1 < NT) ? t + 1 : 0;
        const int kt2 = (t + 2 < NT) ? t + 2 : 0;

        // ---------- q0 ----------
#pragma unroll
        for (int fm = 0; fm < 4; ++fm)
            a[fm] = *(const bf16x8*)&L[c][0][0][(wm0 + fm * 16 + l15) * 32 + (q8 ^ rsw8)];
#pragma unroll
        for (int fn = 0; fn < 4; ++fn)
            b[fn] = *(const bf16x8*)&L[c][1][0][(wn0 + fn * 16 + l15) * 32 + (q8 ^ rsw8)];
        stage(1, 1, kt1, o);
        GQ_BARRIER();
        GQ_LGKM0();
        __builtin_amdgcn_s_setprio(1);
#pragma unroll
        for (int fm = 0; fm < 4; ++fm)
#pragma unroll
            for (int fn = 0; fn < 4; ++fn)
                acc[fm][fn] = __builtin_amdgcn_mfma_f32_16x16x32_bf16(a[fm], b[fn], acc[fm][fn], 0, 0, 0);
        __builtin_amdgcn_s_setprio(0);
        GQ_BARRIER();

        // ---------- q1 ----------
#pragma unroll
        for (int fn = 0; fn < 4; ++fn)
            b[fn] = *(const bf16x8*)&L[c][1][0][(wn0 + 64 + fn * 16 + l15) * 32 + (q8 ^ rsw8)];
        stage(0, 0, kt2, c);
        GQ_BARRIER();
        GQ_LGKM0();
        __builtin_amdgcn_s_setprio(1);
#pragma unroll
        for (int fm = 0; fm < 4; ++fm)
#pragma unroll
            for (int fn = 0; fn < 4; ++fn)
                acc[fm][4 + fn] = __builtin_amdgcn_mfma_f32_16x16x32_bf16(a[fm], b[fn], acc[fm][4 + fn], 0, 0, 0);
        __builtin_amdgcn_s_setprio(0);
        GQ_BARRIER();

        // ---------- q2 ----------
#pragma unroll
        for (int fm = 0; fm < 4; ++fm)
            a[fm] = *(const bf16x8*)&L[c][0][1][(wm0 + fm * 16 + l15) * 32 + (q8 ^ rsw8)];
#pragma unroll
        for (int fn = 0; fn < 4; ++fn)
            b[fn] = *(const bf16x8*)&L[c][1][1][(wn0 + fn * 16 + l15) * 32 + (q8 ^ rsw8)];
        stage(1, 0, kt2, c);
        GQ_BARRIER();
        GQ_LGKM0();
        __builtin_amdgcn_s_setprio(1);
#pragma unroll
        for (int fm = 0; fm < 4; ++fm)
#pragma unroll
            for (int fn = 0; fn < 4; ++fn)
                acc[fm][fn] = __builtin_amdgcn_mfma_f32_16x16x32_bf16(a[fm], b[fn], acc[fm][fn], 0, 0, 0);
        __builtin_amdgcn_s_setprio(0);
        GQ_BARRIER();

        // ---------- q3 ----------
#pragma unroll
        for (int fn = 0; fn < 4; ++fn)
            b[fn] = *(const bf16x8*)&L[c][1][1][(wn0 + 64 + fn * 16 + l15) * 32 + (q8 ^ rsw8)];
        stage(0, 1, kt2, c);
        GQ_BARRIER();
        GQ_LGKM0();
        __builtin_amdgcn_s_setprio(1);
#pragma unroll
        for (int fm = 0; fm < 4; ++fm)
#pragma unroll
            for (int fn = 0; fn < 4; ++fn)
                acc[fm][4 + fn] = __builtin_amdgcn_mfma_f32_16x16x32_bf16(a[fm], b[fn], acc[fm][4 + fn], 0, 0, 0);
        __builtin_amdgcn_s_setprio(0);
        asm volatile("s_waitcnt vmcnt(6)" ::: "memory");
        GQ_BARRIER();
    }

    // ---- epilogue ----
    if (MODE == 3) {
        asm volatile("s_waitcnt vmcnt(0)" ::: "memory");
        GQ_BARRIER();
        const int h = n0 >> 8;
        if (w < 4) {
#pragma unroll
            for (int fm = 0; fm < 4; ++fm)
#pragma unroll
                for (int r = 0; r < 4; ++r) {
                    size_t base = (size_t)(m0 + wm0 + fm * 16 + quad * 4 + r) * 4096
                                  + n0 + wn0 + l15;
#pragma unroll
                    for (int fn = 0; fn < 8; ++fn)
                        ((ushort*)Cv)[base + fn * 16] = f2bf(acc[fm][fn][r]);
                }
        } else {
            ushort* T = &L[0][0][0][0] + (size_t)(w - 4) * (128 * 80);
#pragma unroll
            for (int fm = 0; fm < 4; ++fm)
#pragma unroll
                for (int fn = 0; fn < 8; ++fn) {
                    uint32_t lo = (uint32_t)f2bf(acc[fm][fn][0])
                                | ((uint32_t)f2bf(acc[fm][fn][1]) << 16);
                    uint32_t hi2 = (uint32_t)f2bf(acc[fm][fn][2])
                                 | ((uint32_t)f2bf(acc[fm][fn][3]) << 16);
                    uint2 pk; pk.x = lo; pk.y = hi2;
                    *(uint2*)&T[(size_t)(fn * 16 + l15) * 80 + fm * 16 + quad * 4] = pk;
                }
            asm volatile("s_waitcnt lgkmcnt(0)" ::: "memory");
            __builtin_amdgcn_sched_barrier(0);
            const int bh = (m0 >> 11) * 16 + h;
            const int sbase = (m0 & 2047) + (w & 3) * 64;
            ushort* vT = (ushort*)Cv2;
#pragma unroll
            for (int j = 0; j < 16; ++j) {
                int cc = j * 64 + lane;
                int vd = cc >> 3;
                int s8 = (cc & 7) * 8;
                bf16x8 v = *(const bf16x8*)&T[(size_t)vd * 80 + s8];
                *(bf16x8*)(vT + ((size_t)bh * 128 + vd) * 2048 + sbase + s8) = v;
            }
        }
        return;
    }
#pragma unroll
    for (int fm = 0; fm < 4; ++fm)
#pragma unroll
        for (int r = 0; r < 4; ++r) {
            int row = m0 + wm0 + fm * 16 + quad * 4 + r;
            if (MODE == 2) {
                if (n0 < 3072) {
                    size_t base = (size_t)row * 3072 + n0 + wn0 + l15;
#pragma unroll
                    for (int fn = 0; fn < 8; ++fn)
                        ((ushort*)Cv)[base + fn * 16] = f2bf(acc[fm][fn][r]);
                } else {
                    size_t base = (size_t)row * CKV_P_ + (n0 - 3072) + wn0 + l15;
#pragma unroll
                    for (int fn = 0; fn < 8; ++fn)
                        ((float*)Cv2)[base + fn * 16] = acc[fm][fn][r];
                }
            } else {
                size_t base = (size_t)row * N + n0 + wn0 + l15;
#pragma unroll
                for (int fn = 0; fn < 8; ++fn) {
                    float v = acc[fm][fn][r];
                    if (MODE == 1) ((ushort*)Cv)[base + fn * 16] = f2bf(v);
                    else           ((float*)Cv)[base + fn * 16] = v;
                }
            }
        }
}

// ============================================================================
// 256x128-tile GEMM, 2 phases/K-tile (wo; round-9 coalesced staging, proven)
// ============================================================================
template <int OUT_BF16>
__global__ __launch_bounds__(512, 2) void gemm_bn128(
    const ushort* __restrict__ A, const ushort* __restrict__ Bw,
    void* __restrict__ Cv, int N, int K, int nbx)
{
    __shared__ __align__(16) ushort LA[2][2][8192];   // 64 KB
    __shared__ __align__(16) ushort LB[2][2][4096];   // 32 KB

    const int tid = threadIdx.x;
    const int lane = tid & 63;
    const int w = tid >> 6;
    const int l15 = lane & 15, quad = lane >> 4;
    const int q8 = quad * 8;
    const int rsw8 = ((l15 >> 1) & 3) * 8;

    const int nwg = (int)gridDim.x;
    const int cpx = nwg >> 3;
    const int lin = (int)blockIdx.x;
    const int swz = (lin & 7) * cpx + (lin >> 3);
    const int m0 = (swz / nbx) * 256;
    const int n0 = (swz % nbx) * 128;

    const int wm0 = (w & 3) * 64;
    const int wn0 = (w >> 2) * 64;

    const int NT = K >> 6;

    f32x4 acc[4][4];
#pragma unroll
    for (int i = 0; i < 4; ++i)
#pragma unroll
        for (int j = 0; j < 4; ++j) acc[i][j] = (f32x4){0.f, 0.f, 0.f, 0.f};

    const int srow = lane >> 2;
    const int scg  = (lane & 3) ^ ((lane >> 3) & 3);

    auto stageA = [&](int kh, int kt, int buf) {
#pragma unroll
        for (int j = 0; j < 2; ++j) {
            int ci = w + j * 8;
            ushort* dst = &LA[buf][kh][ci * 512 + lane * 8];
            int row = ci * 16 + srow;
            const ushort* src = A + (size_t)(m0 + row) * K
                                + kt * 64 + kh * 32 + scg * 8;
            gll16(src, dst);
        }
    };
    auto stageB = [&](int kt, int buf) {
#pragma unroll
        for (int j = 0; j < 2; ++j) {         // j = kh
            ushort* dst = &LB[buf][j][(w * 64 + lane) * 8];
            int row = w * 16 + srow;
            const ushort* src = Bw + (size_t)(n0 + row) * K
                                + kt * 64 + j * 32 + scg * 8;
            gll16(src, dst);
        }
    };

    // ---- prologue: tile0 {A0,A1,B} + A0(tile1) = 8 loads ----
    stageA(0, 0, 0); stageA(1, 0, 0); stageB(0, 0);
    stageA(0, (NT > 1) ? 1 : 0, 1);
    asm volatile("s_waitcnt vmcnt(2)" ::: "memory");
    GQ_BARRIER();

    bf16x8 a[4], b[4];

    for (int t = 0; t < NT; ++t) {
        const int c = t & 1, o = c ^ 1;
        const int kt1 = (t + 1 < NT) ? t + 1 : 0;
        const int kt2 = (t + 2 < NT) ? t + 2 : 0;

        // ---------- ph0 (kh0) ----------
#pragma unroll
        for (int fm = 0; fm < 4; ++fm)
            a[fm] = *(const bf16x8*)&LA[c][0][(wm0 + fm * 16 + l15) * 32 + (q8 ^ rsw8)];
#pragma unroll
        for (int fn = 0; fn < 4; ++fn)
            b[fn] = *(const bf16x8*)&LB[c][0][(wn0 + fn * 16 + l15) * 32 + (q8 ^ rsw8)];
        stageA(1, kt1, o); stageB(kt1, o);
        GQ_BARRIER();
        GQ_LGKM0();
        __builtin_amdgcn_s_setprio(1);
#pragma unroll
        for (int fm = 0; fm < 4; ++fm)
#pragma unroll
            for (int fn = 0; fn < 4; ++fn)
                acc[fm][fn] = __builtin_amdgcn_mfma_f32_16x16x32_bf16(a[fm], b[fn], acc[fm][fn], 0, 0, 0);
        __builtin_amdgcn_s_setprio(0);
        GQ_BARRIER();

        // ---------- ph1 (kh1) ----------
#pragma unroll
        for (int fm = 0; fm < 4; ++fm)
            a[fm] = *(const bf16x8*)&LA[c][1][(wm0 + fm * 16 + l15) * 32 + (q8 ^ rsw8)];
#pragma unroll
        for (int fn = 0; fn < 4; ++fn)
            b[fn] = *(const bf16x8*)&LB[c][1][(wn0 + fn * 16 + l15) * 32 + (q8 ^ rsw8)];
        stageA(0, kt2, c);
        GQ_BARRIER();
        GQ_LGKM0();
        __builtin_amdgcn_s_setprio(1);
#pragma unroll
        for (int fm = 0; fm < 4; ++fm)
#pragma unroll
            for (int fn = 0; fn < 4; ++fn)
                acc[fm][fn] = __builtin_amdgcn_mfma_f32_16x16x32_bf16(a[fm], b[fn], acc[fm][fn], 0, 0, 0);
        __builtin_amdgcn_s_setprio(0);
        asm volatile("s_waitcnt vmcnt(2)" ::: "memory");
        GQ_BARRIER();
    }

    // ---- epilogue ----
#pragma unroll
    for (int fm = 0; fm < 4; ++fm)
#pragma unroll
        for (int r = 0; r < 4; ++r) {
            size_t base = (size_t)(m0 + wm0 + fm * 16 + quad * 4 + r) * N + n0 + wn0 + l15;
#pragma unroll
            for (int fn = 0; fn < 4; ++fn) {
                float v = acc[fm][fn][r];
                if (OUT_BF16) ((ushort*)Cv)[base + fn * 16] = f2bf(v);
                else          ((float*)Cv)[base + fn * 16] = v;
            }
        }
}

// ============================================================================
// Fused cast kernel (unchanged)
// ============================================================================
__global__ __launch_bounds__(256) void cast_all(
    const float* __restrict__ x, const float* __restrict__ wq,
    const float* __restrict__ wkva, const float* __restrict__ wkvb,
    const float* __restrict__ wo,
    ushort* __restrict__ xb, ushort* __restrict__ wc,
    ushort* __restrict__ wkvb_bf, ushort* __restrict__ wo_bf)
{
    size_t i = ((size_t)blockIdx.x * 256 + threadIdx.x) * 8;
    const float* s; ushort* d;
    if (i < 8388608)        { s = x + i;                  d = xb + i; }
    else if (i < 14680064)  { s = wq + (i - 8388608);     d = wc + (i - 8388608); }
    else if (i < 15859712)  { s = wkva + (i - 14680064);  d = wc + (i - 8388608); }
    else if (i < 16252928)  {
        ushort4 z = {0, 0, 0, 0};
        ushort* dz = wc + (i - 8388608);
        *(ushort4*)dz = z; *(ushort4*)(dz + 4) = z;
        return;
    }
    else if (i < 18350080)  { s = wkvb + (i - 16252928);  d = wkvb_bf + (i - 16252928); }
    else                    { s = wo + (i - 18350080);    d = wo_bf + (i - 18350080); }
    float4 a = *(const float4*)s;
    float4 b = *(const float4*)(s + 4);
    ushort4 o0, o1;
    o0.x = f2bf(a.x); o0.y = f2bf(a.y); o0.z = f2bf(a.z); o0.w = f2bf(a.w);
    o1.x = f2bf(b.x); o1.y = f2bf(b.y); o1.z = f2bf(b.z); o1.w = f2bf(b.w);
    *(ushort4*)d = o0;
    *(ushort4*)(d + 4) = o1;
}

// ============================================================================
// Fused RMSNorm + RoPE-k (unchanged, pitch 768)
// ============================================================================
__global__ __launch_bounds__(256) void rmsnorm_rope_k(
    const float* __restrict__ ckv, const float* __restrict__ nw,
    const float* __restrict__ rope_cache,
    ushort* __restrict__ cnorm, ushort* __restrict__ krb)
{
    const int lane = threadIdx.x & 63;
    const int row = blockIdx.x * 4 + (threadIdx.x >> 6);
    const float* src = ckv + (size_t)row * CKV_P_;
    float4 a = *(const float4*)(src + lane * 4);
    float4 b = *(const float4*)(src + 256 + lane * 4);
    float ss = a.x*a.x + a.y*a.y + a.z*a.z + a.w*a.w
             + b.x*b.x + b.y*b.y + b.z*b.z + b.w*b.w;
#pragma unroll
    for (int off = 32; off > 0; off >>= 1) ss += __shfl_xor(ss, off, 64);
    float rs = rsqrtf(ss * (1.0f / 512.0f) + EPS_);
    float4 w0 = *(const float4*)(nw + lane * 4);
    float4 w1 = *(const float4*)(nw + 256 + lane * 4);
    ushort* dst = cnorm + (size_t)row * KV_LORA_;
    ushort4 o0, o1;
    o0.x = f2bf(a.x*rs*w0.x); o0.y = f2bf(a.y*rs*w0.y);
    o0.z = f2bf(a.z*rs*w0.z); o0.w = f2bf(a.w*rs*w0.w);
    o1.x = f2bf(b.x*rs*w1.x); o1.y = f2bf(b.y*rs*w1.y);
    o1.z = f2bf(b.z*rs*w1.z); o1.w = f2bf(b.w*rs*w1.w);
    *(ushort4*)(dst + lane * 4) = o0;
    *(ushort4*)(dst + 256 + lane * 4) = o1;

    float v = src[KV_LORA_ + lane];
    float other = __shfl_xor(v, 32, 64);
    float rot = (lane < 32) ? -other : other;
    int s = row & (S_ - 1);
    float c  = rope_cache[s * (2 * ROPE_D_) + lane];
    float sn = rope_cache[s * (2 * ROPE_D_) + ROPE_D_ + lane];
    krb[(size_t)row * ROPE_D_ + lane] = f2bf(v * c + rot * sn);
}

// ============================================================================
// MFMA flash attention v8 = v7 + 2 blocks/CU + exp2-domain softmax + cvt_pk.
//  - Grid 512, ONE q-tile per block.  Dispatch round-robins blockIdx across
//    XCDs then CUs, so blocks lin and lin+256 co-locate on a CU: we give them
//    the SAME bh with COMPLEMENTARY q-tiles (j, 15-j) -> exactly 34 iters and
//    shared K/V per CU.  LDS 80KB x 2 = 160KB/CU; VGPR <= 128 enforced via
//    __launch_bounds__(512,4) -> 4 waves/SIMD (was 2): latency hiding.
//  - Softmax in exp2 domain: scores scaled by 192^-.5*log2e once; v_exp_f32
//    is natively 2^x (deletes 16 muls/iter); defer-max THR = 8*log2e.
//  - P->bf16 pack via v_cvt_pk_bf16_f32 (T12): 8 instrs replace ~64 VALU.
// ============================================================================
__global__ __launch_bounds__(512, 4) void mla_attn_mfma8(
    const ushort* __restrict__ qb, const ushort* __restrict__ kvb,
    const ushort* __restrict__ krb, const ushort* __restrict__ vT,
    const float* __restrict__ rope_cache, ushort* __restrict__ attn)
{
    __shared__ __align__(16) ushort LDSU[40960];   // 80 KB
    const int KNo[2] = {0, 8192};
    const int KRo[2] = {16384, 20480};
    const int VVo[2] = {24576, 32768};

    const int tid = threadIdx.x;
    const int lane = tid & 63;
    const int w = tid >> 6;               // wave 0..7
    const int l31 = lane & 31, hi = lane >> 5;
    const int band = w & 3;               // 32-row q band
    const int koff = (w >> 2) * 32;       // k half of 64-row K tile

    // Pair mapping: lin and lin+256 -> same (xcd, cu) under round-robin
    // dispatch; same bh, complementary qt.
    const int lin = (int)blockIdx.x;
    const int r256 = lin & 255, sl = lin >> 8;
    const int xcd = r256 & 7, cu = r256 >> 3;       // cu in [0,32)
    const int bh = xcd * 4 + (cu >> 3);             // 4 bh per XCD (L2-fit)
    const int jj = cu & 7;
    const int qt = sl ? (15 - jj) : jj;
    const int b = bh >> 4, h = bh & 15;
    const size_t bS = (size_t)b * S_;
    const float sc_l2e = 0.10411789f;     // 192^-0.5 * log2(e)

    auto stage = [&](int kbase, int bufi) {
        // K-nope: 64 rows x 16 chunks, 16 lanes/row
#pragma unroll
        for (int j = 0; j < 2; ++j) {
            int g = (j * 8 + w) * 64 + lane;
            int row = g >> 4;
            int d8 = (g & 15) ^ (row & 7);
            ushort* dst = &LDSU[KNo[bufi] + g * 8];
            const ushort* src = kvb + (bS + kbase + row) * 4096 + h * 256 + d8 * 8;
            gll16(src, dst);
        }
        // K-rope: 64 rows x 8 chunks, 8 lanes/row
        {
            int g = w * 64 + lane;
            int row = g >> 3;
            int r8 = (g & 7) ^ (row & 7);
            ushort* dst = &LDSU[KRo[bufi] + g * 8];
            const ushort* src = krb + (bS + kbase + row) * 64 + r8 * 8;
            gll16(src, dst);
        }
        // V: 128 vd-rows x 8 chunks, 8 lanes/row
#pragma unroll
        for (int j = 0; j < 2; ++j) {
            int g = (j * 8 + w) * 64 + lane;
            int vd = g >> 3;
            int kc = (g & 7) ^ (vd & 7);
            ushort* dst = &LDSU[VVo[bufi] + g * 8];
            const ushort* src = vT + ((size_t)bh * 128 + vd) * 2048 + kbase + kc * 8;
            gll16(src, dst);
        }
    };

    const int qbase = qt * 128;
    const int nkt = 2 * qt + 2;
    const int bmin = qbase + band * 32;   // wave's first q row

    stage(0, 0);

    // ---- Q fragments with fused RoPE on chunks 8..11 (cols 128..191) ----
    bf16x8 qf[12];
    {
        const ushort* qrow = qb + (bS + bmin + l31) * (size_t)(H_ * Q_D_) + h * Q_D_;
#pragma unroll
        for (int c = 0; c < 8; ++c)
            qf[c] = *(const bf16x8*)(qrow + c * 16 + hi * 8);
        bf16x8 q8  = *(const bf16x8*)(qrow + 128 + hi * 8);
        bf16x8 q9  = *(const bf16x8*)(qrow + 144 + hi * 8);
        bf16x8 q10 = *(const bf16x8*)(qrow + 160 + hi * 8);
        bf16x8 q11 = *(const bf16x8*)(qrow + 176 + hi * 8);
        const float* rc = rope_cache + (size_t)(bmin + l31) * 128 + hi * 8;
        f32x4 c8a = *(const f32x4*)(rc + 0),  c8b = *(const f32x4*)(rc + 4);
        f32x4 c9a = *(const f32x4*)(rc + 16), c9b = *(const f32x4*)(rc + 20);
        f32x4 cAa = *(const f32x4*)(rc + 32), cAb = *(const f32x4*)(rc + 36);
        f32x4 cBa = *(const f32x4*)(rc + 48), cBb = *(const f32x4*)(rc + 52);
        f32x4 s8a = *(const f32x4*)(rc + 64), s8b = *(const f32x4*)(rc + 68);
        f32x4 s9a = *(const f32x4*)(rc + 80), s9b = *(const f32x4*)(rc + 84);
        f32x4 sAa = *(const f32x4*)(rc + 96), sAb = *(const f32x4*)(rc + 100);
        f32x4 sBa = *(const f32x4*)(rc + 112), sBb = *(const f32x4*)(rc + 116);
        bf16x8 o8, o9, o10, o11;
#pragma unroll
        for (int e = 0; e < 4; ++e) {
            float a8 = bf2f((ushort)q8[e]),  b8 = bf2f((ushort)q8[e + 4]);
            float a9 = bf2f((ushort)q9[e]),  b9 = bf2f((ushort)q9[e + 4]);
            float aA = bf2f((ushort)q10[e]), bA = bf2f((ushort)q10[e + 4]);
            float aB = bf2f((ushort)q11[e]), bB = bf2f((ushort)q11[e + 4]);
            o8[e]      = (short)f2bf(a8 * c8a[e] - aA * s8a[e]);
            o8[e + 4]  = (short)f2bf(b8 * c8b[e] - bA * s8b[e]);
            o9[e]      = (short)f2bf(a9 * c9a[e] - aB * s9a[e]);
            o9[e + 4]  = (short)f2bf(b9 * c9b[e] - bB * s9b[e]);
            o10[e]     = (short)f2bf(aA * cAa[e] + a8 * sAa[e]);
            o10[e + 4] = (short)f2bf(bA * cAb[e] + b8 * sAb[e]);
            o11[e]     = (short)f2bf(aB * cBa[e] + a9 * sBa[e]);
            o11[e + 4] = (short)f2bf(bB * cBb[e] + b9 * sBb[e]);
        }
        qf[8] = o8; qf[9] = o9; qf[10] = o10; qf[11] = o11;
    }

    f32x16 ov[4];
#pragma unroll
    for (int vt = 0; vt < 4; ++vt)
#pragma unroll
        for (int r = 0; r < 16; ++r) ov[vt][r] = 0.f;
    float m_run = -3e38f, lsum = 0.f;     // m_run in log2 domain

    __syncthreads();                      // tile 0 visible

    const int krow = koff + l31;
    const int kx7 = krow & 7;
    const int vx7 = l31 & 7;

    for (int kt = 0; kt < nkt; ++kt) {
        const int kb = kt * 64;
        const int cur = kt & 1;
        if (kt + 1 < nkt) stage((kt + 1) * 64, cur ^ 1);

        const int kg = kb + koff;         // wave's 32-k strip start
        if (kg <= bmin + 31) {            // strip not fully masked
            f32x16 sc;
#pragma unroll
            for (int r = 0; r < 16; ++r) sc[r] = 0.f;
            __builtin_amdgcn_s_setprio(1);
#pragma unroll
            for (int c = 0; c < 12; ++c) {
                const bf16x8* kp;
                if (c < 8)
                    kp = (const bf16x8*)&LDSU[KNo[cur] + (krow * 16 + ((c * 2 + hi) ^ kx7)) * 8];
                else
                    kp = (const bf16x8*)&LDSU[KRo[cur] + (krow * 8 + (((c - 8) * 2 + hi) ^ kx7)) * 8];
                sc = __builtin_amdgcn_mfma_f32_32x32x16_bf16(*kp, qf[c], sc, 0, 0, 0);
            }
            __builtin_amdgcn_s_setprio(0);

            const bool need_mask = (kg == bmin);   // only diagonal strips
            float p[16]; float mx = -3e38f;
#pragma unroll
            for (int r = 0; r < 16; ++r) {
                float v = sc[r] * sc_l2e;          // log2-domain score
                if (need_mask) {
                    int kr = (r & 3) + 8 * (r >> 2) + 4 * hi;
                    if (kr > l31) v = -3e38f;
                }
                p[r] = v; mx = fmaxf(mx, v);
            }
            mx = fmaxf(mx, __shfl_xor(mx, 32, 64));   // full 64-k row max
            if (!__all(mx - m_run <= 11.5416f)) {     // 8 * log2(e)
                float mn = fmaxf(mx, m_run);
                float al;
                asm("v_exp_f32 %0, %1" : "=v"(al) : "v"(m_run - mn));  // 2^x
                m_run = mn; lsum *= al;
#pragma unroll
                for (int vt = 0; vt < 4; ++vt)
#pragma unroll
                    for (int r = 0; r < 16; ++r) ov[vt][r] *= al;
            }
            float s_loc = 0.f;
#pragma unroll
            for (int r = 0; r < 16; ++r) {
                float e;
                asm("v_exp_f32 %0, %1" : "=v"(e) : "v"(p[r] - m_run));  // 2^x
                p[r] = e; s_loc += e;
            }
            lsum += s_loc + __shfl_xor(s_loc, 32, 64);

            uint32_t w8[8];
#pragma unroll
            for (int m = 0; m < 8; ++m)
                asm("v_cvt_pk_bf16_f32 %0, %1, %2"
                    : "=v"(w8[m]) : "v"(p[2 * m]), "v"(p[2 * m + 1]));
            bf16x8 pb[2];
#pragma unroll
            for (int c = 0; c < 2; ++c) {
                uint32_t wd[4];
#pragma unroll
                for (int par = 0; par < 2; ++par) {
                    uint32_t a  = w8[4 * c + par];
                    uint32_t bb = w8[4 * c + 2 + par];
                    uint32_t t  = __shfl_xor(bb, 32, 64);
                    uint32_t t2 = __shfl_xor(a, 32, 64);
                    wd[par]     = hi ? t : a;
                    wd[par + 2] = hi ? bb : t2;
                }
                union { uint32_t u[4]; bf16x8 v; } cvt;
                cvt.u[0] = wd[0]; cvt.u[1] = wd[1]; cvt.u[2] = wd[2]; cvt.u[3] = wd[3];
                pb[c] = cvt.v;
            }

            __builtin_amdgcn_s_setprio(1);
#pragma unroll
            for (int vt = 0; vt < 4; ++vt)
#pragma unroll
                for (int cc = 0; cc < 2; ++cc) {
                    int vd = vt * 32 + l31;
                    int k8 = (koff >> 3) + cc * 2 + hi;
                    bf16x8 vf = *(const bf16x8*)
                        &LDSU[VVo[cur] + (vd * 8 + (k8 ^ vx7)) * 8];
                    ov[vt] = __builtin_amdgcn_mfma_f32_32x32x16_bf16(vf, pb[cc], ov[vt], 0, 0, 0);
                }
            __builtin_amdgcn_s_setprio(0);
        }
        __syncthreads();   // publish prefetched tile; WAR-protect buffers
    }

    float* mrg = (float*)LDSU;
    if (w >= 4) {
        float* dst = mrg + (size_t)((w - 4) * 64 + lane) * 68;
#pragma unroll
        for (int vt = 0; vt < 4; ++vt)
#pragma unroll
            for (int g = 0; g < 4; ++g) {
                f32x4 v4v = { ov[vt][g * 4 + 0], ov[vt][g * 4 + 1],
                              ov[vt][g * 4 + 2], ov[vt][g * 4 + 3] };
                *(f32x4*)(dst + vt * 16 + g * 4) = v4v;
            }
        dst[64] = m_run; dst[65] = lsum;
    }
    __syncthreads();
    if (w < 4) {
        const float* srcm = mrg + (size_t)(w * 64 + lane) * 68;
        float mB = srcm[64], lB = srcm[65];
        float M = fmaxf(m_run, mB);
        float eA, eB;
        asm("v_exp_f32 %0, %1" : "=v"(eA) : "v"(m_run - M));   // 2^x
        asm("v_exp_f32 %0, %1" : "=v"(eB) : "v"(mB - M));
        float L = lsum * eA + lB * eB;
        float inv = 1.0f / L;
        size_t obase = (bS + bmin + l31) * (size_t)(H_ * V_D_) + h * V_D_;
#pragma unroll
        for (int vt = 0; vt < 4; ++vt)
#pragma unroll
            for (int g = 0; g < 4; ++g) {
                ushort4 o;
                o.x = f2bf((ov[vt][g*4+0] * eA + srcm[vt*16+g*4+0] * eB) * inv);
                o.y = f2bf((ov[vt][g*4+1] * eA + srcm[vt*16+g*4+1] * eB) * inv);
                o.z = f2bf((ov[vt][g*4+2] * eA + srcm[vt*16+g*4+2] * eB) * inv);
                o.w = f2bf((ov[vt][g*4+3] * eA + srcm[vt*16+g*4+3] * eB) * inv);
                *(ushort4*)(attn + obase + vt * 32 + g * 8 + hi * 4) = o;
            }
    }
}

// ============================================================================
// launch — workspace ~138 MB (round-6..9 layout, unchanged)
// ============================================================================
extern "C" void kernel_launch(void* const* d_in, const int* in_sizes, int n_in,
                              void* d_out, int out_size, void* d_ws, size_t ws_size,
                              hipStream_t stream)
{
    const float* x          = (const float*)d_in[0];
    const float* rope_cache = (const float*)d_in[1];
    const float* wq         = (const float*)d_in[2];
    const float* wkva       = (const float*)d_in[3];
    const float* norm_w     = (const float*)d_in[4];
    const float* wkvb       = (const float*)d_in[5];
    const float* wo         = (const float*)d_in[6];
    float* out = (float*)d_out;

    char* p = (char*)d_ws;
    ushort* xb       = (ushort*)p; p += (size_t)BS_ * DIM_ * 2;        // 16.8 MB
    ushort* q_bf     = (ushort*)p; p += (size_t)BS_ * H_ * Q_D_ * 2;   // 25.2 MB
    float*  ckv      = (float*) p; p += (size_t)BS_ * CKV_P_ * 4;      // 12.6 MB
    ushort* cnorm_bf = (ushort*)p; p += (size_t)BS_ * KV_LORA_ * 2;    //  4.2 MB
    ushort* kvb      = (ushort*)p; p += (size_t)BS_ * 4096 * 2;        // 33.6 MB
    ushort* attn_bf  = (ushort*)p; p += (size_t)BS_ * 2048 * 2;        // 16.8 MB
    ushort* krb      = (ushort*)p; p += (size_t)BS_ * ROPE_D_ * 2;     //  0.5 MB
    ushort* wc_bf    = (ushort*)p; p += (size_t)3840 * DIM_ * 2;       // 15.7 MB
    ushort* wkvb_bf  = (ushort*)p; p += (size_t)4096 * KV_LORA_ * 2;   //  4.2 MB
    ushort* wo_bf    = (ushort*)p; p += (size_t)DIM_ * 2048 * 2;       //  8.4 MB
    ushort* vT       = xb;   // alias: xb dead after GEMM 1; same size

    // 0. all input casts in one dispatch
    cast_all<<<11008, dim3(256), 0, stream>>>(
        x, wq, wkva, wkvb, wo, xb, wc_bf, wkvb_bf, wo_bf);

    // 1. fused: q_bf = x @ wq^T (bf16) and ckv = x @ wkva^T (fp32, pitch 768)
    gemm256_8ph<2><<<dim3(16 * 15), dim3(512), 0, stream>>>(
        xb, wc_bf, q_bf, ckv, 0, DIM_, 15);
    // 2. cnorm + krb fused
    rmsnorm_rope_k<<<BS_ / 4, dim3(256), 0, stream>>>(
        ckv, norm_w, rope_cache, cnorm_bf, krb);
    // 3. kvb (K-nope) + vT (V transposed) = cnorm @ wkvb^T, fused epilogue
    gemm256_8ph<3><<<dim3(16 * 16), dim3(512), 0, stream>>>(
        cnorm_bf, wkvb_bf, kvb, vT, 4096, KV_LORA_, 16);
    // 4. flash attention v8 (2 blocks/CU, paired q-tiles) -> attn_bf
    mla_attn_mfma8<<<dim3(512), dim3(512), 0, stream>>>(
        q_bf, kvb, krb, vT, rope_cache, attn_bf);
    // 5. out = attn @ wo^T        (4096 x 2048 x 2048), fp32, 256 blocks
    gemm_bn128<0><<<dim3(16 * 16), dim3(512), 0, stream>>>(
        attn_bf, wo_bf, out, 2048, 2048, 16);
}

// Round 11
// 351.820 us; speedup vs baseline: 1.3546x; 1.3546x over previous
//
#include <hip/hip_runtime.h>
#include <cstdint>
#include <cstddef>

// ---- problem constants ----
#define B_      2
#define S_      2048
#define DIM_    2048
#define H_      16
#define KV_LORA_ 512
#define NOPE_D_ 128
#define ROPE_D_ 64
#define V_D_    128
#define Q_D_    192          // NOPE_D + ROPE_D
#define EPS_    1e-6f
#define BS_     (B_ * S_)    // 4096 rows
#define CKV_P_  768          // ckv row pitch (576 real cols, padded to 768)

typedef __attribute__((ext_vector_type(8))) short bf16x8;
typedef __attribute__((ext_vector_type(4))) float f32x4;
typedef __attribute__((ext_vector_type(16))) float f32x16;

__device__ __forceinline__ ushort f2bf(float f) {
    union { float f; uint32_t u; } v; v.f = f;
    uint32_t u = v.u + 0x7fff + ((v.u >> 16) & 1);  // RNE
    return (ushort)(u >> 16);
}
__device__ __forceinline__ float bf2f(ushort u) {
    union { uint32_t u; float f; } v; v.u = (uint32_t)u << 16; return v.f;
}
__device__ __forceinline__ void gll16(const void* g, void* l) {
    __builtin_amdgcn_global_load_lds(
        (const __attribute__((address_space(1))) unsigned int*)g,
        (__attribute__((address_space(3))) unsigned int*)l, 16, 0, 0);
}

#define GQ_BARRIER()  __builtin_amdgcn_s_barrier()
#define GQ_LGKM0()    do { asm volatile("s_waitcnt lgkmcnt(0)" ::: "memory"); \
                           __builtin_amdgcn_sched_barrier(0); } while (0)

// ============================================================================
// 256x256 8-phase bf16 GEMM (round-8 coalesced+swizzled staging, proven).
// MODE: 0 = f32 pitch N, 1 = bf16 pitch N,
//       2 = split (q-proj bf16 pitch 3072 | ckv f32 pitch 768),
//       3 = kvb + fused V-transpose.
// ============================================================================
template <int MODE>
__global__ __launch_bounds__(512, 2) void gemm256_8ph(
    const ushort* __restrict__ A, const ushort* __restrict__ Bw,
    void* __restrict__ Cv, void* __restrict__ Cv2, int N, int K, int nbx)
{
    __shared__ __align__(16) ushort L[2][2][2][8192];   // 128 KB (slot=16KB)

    const int tid = threadIdx.x;
    const int lane = tid & 63;
    const int w = tid >> 6;
    const int l15 = lane & 15, quad = lane >> 4;
    const int q8 = quad * 8;
    const int rsw8 = ((l15 >> 1) & 3) * 8;    // read-side XOR term (ushorts)

    const int nwg = (int)gridDim.x;
    const int cpx = nwg >> 3;
    const int lin = (int)blockIdx.x;
    const int swz = (lin & 7) * cpx + (lin >> 3);
    const int m0 = (swz / nbx) * 256;
    const int n0 = (swz % nbx) * 256;

    const int wm0 = (w & 3) * 64;
    const int wn0 = (w >> 2) * 128;

    const int NT = K >> 6;

    f32x4 acc[4][8];
#pragma unroll
    for (int i = 0; i < 4; ++i)
#pragma unroll
        for (int j = 0; j < 8; ++j) acc[i][j] = (f32x4){0.f, 0.f, 0.f, 0.f};

    const int srow = lane >> 2;                        // row within 16-row chunk
    const int scg  = (lane & 3) ^ ((lane >> 3) & 3);   // permuted col-group

    auto stage = [&](int ab, int kh, int kt, int buf) {
#pragma unroll
        for (int j = 0; j < 2; ++j) {
            int ci = w + j * 8;
            ushort* dst = &L[buf][ab][kh][ci * 512 + lane * 8];
            int row = ci * 16 + srow;
            const ushort* src = (ab ? Bw + (size_t)(n0 + row) * K
                                    : A  + (size_t)(m0 + row) * K)
                                + kt * 64 + kh * 32 + scg * 8;
            gll16(src, dst);
        }
    };

    // ---- prologue ----
    stage(0, 0, 0, 0); stage(1, 0, 0, 0); stage(0, 1, 0, 0); stage(1, 1, 0, 0);
    if (NT > 1) { stage(0, 0, 1, 1); stage(1, 0, 1, 1); stage(0, 1, 1, 1); }
    else        { stage(0, 0, 0, 1); stage(1, 0, 0, 1); stage(0, 1, 0, 1); }
    asm volatile("s_waitcnt vmcnt(6)" ::: "memory");
    GQ_BARRIER();

    bf16x8 a[4], b[4];

    for (int t = 0; t < NT; ++t) {
        const int c = t & 1, o = c ^ 1;
        const int kt1 = (t + 1 < NT) ? t + 1 : 0;
        const int kt2 = (t + 2 < NT) ? t + 2 : 0;

        // ---------- q0 ----------
#pragma unroll
        for (int fm = 0; fm < 4; ++fm)
            a[fm] = *(const bf16x8*)&L[c][0][0][(wm0 + fm * 16 + l15) * 32 + (q8 ^ rsw8)];
#pragma unroll
        for (int fn = 0; fn < 4; ++fn)
            b[fn] = *(const bf16x8*)&L[c][1][0][(wn0 + fn * 16 + l15) * 32 + (q8 ^ rsw8)];
        stage(1, 1, kt1, o);
        GQ_BARRIER();
        GQ_LGKM0();
        __builtin_amdgcn_s_setprio(1);
#pragma unroll
        for (int fm = 0; fm < 4; ++fm)
#pragma unroll
            for (int fn = 0; fn < 4; ++fn)
                acc[fm][fn] = __builtin_amdgcn_mfma_f32_16x16x32_bf16(a[fm], b[fn], acc[fm][fn], 0, 0, 0);
        __builtin_amdgcn_s_setprio(0);
        GQ_BARRIER();

        // ---------- q1 ----------
#pragma unroll
        for (int fn = 0; fn < 4; ++fn)
            b[fn] = *(const bf16x8*)&L[c][1][0][(wn0 + 64 + fn * 16 + l15) * 32 + (q8 ^ rsw8)];
        stage(0, 0, kt2, c);
        GQ_BARRIER();
        GQ_LGKM0();
        __builtin_amdgcn_s_setprio(1);
#pragma unroll
        for (int fm = 0; fm < 4; ++fm)
#pragma unroll
            for (int fn = 0; fn < 4; ++fn)
                acc[fm][4 + fn] = __builtin_amdgcn_mfma_f32_16x16x32_bf16(a[fm], b[fn], acc[fm][4 + fn], 0, 0, 0);
        __builtin_amdgcn_s_setprio(0);
        GQ_BARRIER();

        // ---------- q2 ----------
#pragma unroll
        for (int fm = 0; fm < 4; ++fm)
            a[fm] = *(const bf16x8*)&L[c][0][1][(wm0 + fm * 16 + l15) * 32 + (q8 ^ rsw8)];
#pragma unroll
        for (int fn = 0; fn < 4; ++fn)
            b[fn] = *(const bf16x8*)&L[c][1][1][(wn0 + fn * 16 + l15) * 32 + (q8 ^ rsw8)];
        stage(1, 0, kt2, c);
        GQ_BARRIER();
        GQ_LGKM0();
        __builtin_amdgcn_s_setprio(1);
#pragma unroll
        for (int fm = 0; fm < 4; ++fm)
#pragma unroll
            for (int fn = 0; fn < 4; ++fn)
                acc[fm][fn] = __builtin_amdgcn_mfma_f32_16x16x32_bf16(a[fm], b[fn], acc[fm][fn], 0, 0, 0);
        __builtin_amdgcn_s_setprio(0);
        GQ_BARRIER();

        // ---------- q3 ----------
#pragma unroll
        for (int fn = 0; fn < 4; ++fn)
            b[fn] = *(const bf16x8*)&L[c][1][1][(wn0 + 64 + fn * 16 + l15) * 32 + (q8 ^ rsw8)];
        stage(0, 1, kt2, c);
        GQ_BARRIER();
        GQ_LGKM0();
        __builtin_amdgcn_s_setprio(1);
#pragma unroll
        for (int fm = 0; fm < 4; ++fm)
#pragma unroll
            for (int fn = 0; fn < 4; ++fn)
                acc[fm][4 + fn] = __builtin_amdgcn_mfma_f32_16x16x32_bf16(a[fm], b[fn], acc[fm][4 + fn], 0, 0, 0);
        __builtin_amdgcn_s_setprio(0);
        asm volatile("s_waitcnt vmcnt(6)" ::: "memory");
        GQ_BARRIER();
    }

    // ---- epilogue ----
    if (MODE == 3) {
        asm volatile("s_waitcnt vmcnt(0)" ::: "memory");
        GQ_BARRIER();
        const int h = n0 >> 8;
        if (w < 4) {
#pragma unroll
            for (int fm = 0; fm < 4; ++fm)
#pragma unroll
                for (int r = 0; r < 4; ++r) {
                    size_t base = (size_t)(m0 + wm0 + fm * 16 + quad * 4 + r) * 4096
                                  + n0 + wn0 + l15;
#pragma unroll
                    for (int fn = 0; fn < 8; ++fn)
                        ((ushort*)Cv)[base + fn * 16] = f2bf(acc[fm][fn][r]);
                }
        } else {
            ushort* T = &L[0][0][0][0] + (size_t)(w - 4) * (128 * 80);
#pragma unroll
            for (int fm = 0; fm < 4; ++fm)
#pragma unroll
                for (int fn = 0; fn < 8; ++fn) {
                    uint32_t lo = (uint32_t)f2bf(acc[fm][fn][0])
                                | ((uint32_t)f2bf(acc[fm][fn][1]) << 16);
                    uint32_t hi2 = (uint32_t)f2bf(acc[fm][fn][2])
                                 | ((uint32_t)f2bf(acc[fm][fn][3]) << 16);
                    uint2 pk; pk.x = lo; pk.y = hi2;
                    *(uint2*)&T[(size_t)(fn * 16 + l15) * 80 + fm * 16 + quad * 4] = pk;
                }
            asm volatile("s_waitcnt lgkmcnt(0)" ::: "memory");
            __builtin_amdgcn_sched_barrier(0);
            const int bh = (m0 >> 11) * 16 + h;
            const int sbase = (m0 & 2047) + (w & 3) * 64;
            ushort* vT = (ushort*)Cv2;
#pragma unroll
            for (int j = 0; j < 16; ++j) {
                int cc = j * 64 + lane;
                int vd = cc >> 3;
                int s8 = (cc & 7) * 8;
                bf16x8 v = *(const bf16x8*)&T[(size_t)vd * 80 + s8];
                *(bf16x8*)(vT + ((size_t)bh * 128 + vd) * 2048 + sbase + s8) = v;
            }
        }
        return;
    }
#pragma unroll
    for (int fm = 0; fm < 4; ++fm)
#pragma unroll
        for (int r = 0; r < 4; ++r) {
            int row = m0 + wm0 + fm * 16 + quad * 4 + r;
            if (MODE == 2) {
                if (n0 < 3072) {
                    size_t base = (size_t)row * 3072 + n0 + wn0 + l15;
#pragma unroll
                    for (int fn = 0; fn < 8; ++fn)
                        ((ushort*)Cv)[base + fn * 16] = f2bf(acc[fm][fn][r]);
                } else {
                    size_t base = (size_t)row * CKV_P_ + (n0 - 3072) + wn0 + l15;
#pragma unroll
                    for (int fn = 0; fn < 8; ++fn)
                        ((float*)Cv2)[base + fn * 16] = acc[fm][fn][r];
                }
            } else {
                size_t base = (size_t)row * N + n0 + wn0 + l15;
#pragma unroll
                for (int fn = 0; fn < 8; ++fn) {
                    float v = acc[fm][fn][r];
                    if (MODE == 1) ((ushort*)Cv)[base + fn * 16] = f2bf(v);
                    else           ((float*)Cv)[base + fn * 16] = v;
                }
            }
        }
}

// ============================================================================
// 256x128-tile GEMM, 2 phases/K-tile (wo; round-9 coalesced staging, proven)
// ============================================================================
template <int OUT_BF16>
__global__ __launch_bounds__(512, 2) void gemm_bn128(
    const ushort* __restrict__ A, const ushort* __restrict__ Bw,
    void* __restrict__ Cv, int N, int K, int nbx)
{
    __shared__ __align__(16) ushort LA[2][2][8192];   // 64 KB
    __shared__ __align__(16) ushort LB[2][2][4096];   // 32 KB

    const int tid = threadIdx.x;
    const int lane = tid & 63;
    const int w = tid >> 6;
    const int l15 = lane & 15, quad = lane >> 4;
    const int q8 = quad * 8;
    const int rsw8 = ((l15 >> 1) & 3) * 8;

    const int nwg = (int)gridDim.x;
    const int cpx = nwg >> 3;
    const int lin = (int)blockIdx.x;
    const int swz = (lin & 7) * cpx + (lin >> 3);
    const int m0 = (swz / nbx) * 256;
    const int n0 = (swz % nbx) * 128;

    const int wm0 = (w & 3) * 64;
    const int wn0 = (w >> 2) * 64;

    const int NT = K >> 6;

    f32x4 acc[4][4];
#pragma unroll
    for (int i = 0; i < 4; ++i)
#pragma unroll
        for (int j = 0; j < 4; ++j) acc[i][j] = (f32x4){0.f, 0.f, 0.f, 0.f};

    const int srow = lane >> 2;
    const int scg  = (lane & 3) ^ ((lane >> 3) & 3);

    auto stageA = [&](int kh, int kt, int buf) {
#pragma unroll
        for (int j = 0; j < 2; ++j) {
            int ci = w + j * 8;
            ushort* dst = &LA[buf][kh][ci * 512 + lane * 8];
            int row = ci * 16 + srow;
            const ushort* src = A + (size_t)(m0 + row) * K
                                + kt * 64 + kh * 32 + scg * 8;
            gll16(src, dst);
        }
    };
    auto stageB = [&](int kt, int buf) {
#pragma unroll
        for (int j = 0; j < 2; ++j) {         // j = kh
            ushort* dst = &LB[buf][j][(w * 64 + lane) * 8];
            int row = w * 16 + srow;
            const ushort* src = Bw + (size_t)(n0 + row) * K
                                + kt * 64 + j * 32 + scg * 8;
            gll16(src, dst);
        }
    };

    // ---- prologue: tile0 {A0,A1,B} + A0(tile1) = 8 loads ----
    stageA(0, 0, 0); stageA(1, 0, 0); stageB(0, 0);
    stageA(0, (NT > 1) ? 1 : 0, 1);
    asm volatile("s_waitcnt vmcnt(2)" ::: "memory");
    GQ_BARRIER();

    bf16x8 a[4], b[4];

    for (int t = 0; t < NT; ++t) {
        const int c = t & 1, o = c ^ 1;
        const int kt1 = (t + 1 < NT) ? t + 1 : 0;
        const int kt2 = (t + 2 < NT) ? t + 2 : 0;

        // ---------- ph0 (kh0) ----------
#pragma unroll
        for (int fm = 0; fm < 4; ++fm)
            a[fm] = *(const bf16x8*)&LA[c][0][(wm0 + fm * 16 + l15) * 32 + (q8 ^ rsw8)];
#pragma unroll
        for (int fn = 0; fn < 4; ++fn)
            b[fn] = *(const bf16x8*)&LB[c][0][(wn0 + fn * 16 + l15) * 32 + (q8 ^ rsw8)];
        stageA(1, kt1, o); stageB(kt1, o);
        GQ_BARRIER();
        GQ_LGKM0();
        __builtin_amdgcn_s_setprio(1);
#pragma unroll
        for (int fm = 0; fm < 4; ++fm)
#pragma unroll
            for (int fn = 0; fn < 4; ++fn)
                acc[fm][fn] = __builtin_amdgcn_mfma_f32_16x16x32_bf16(a[fm], b[fn], acc[fm][fn], 0, 0, 0);
        __builtin_amdgcn_s_setprio(0);
        GQ_BARRIER();

        // ---------- ph1 (kh1) ----------
#pragma unroll
        for (int fm = 0; fm < 4; ++fm)
            a[fm] = *(const bf16x8*)&LA[c][1][(wm0 + fm * 16 + l15) * 32 + (q8 ^ rsw8)];
#pragma unroll
        for (int fn = 0; fn < 4; ++fn)
            b[fn] = *(const bf16x8*)&LB[c][1][(wn0 + fn * 16 + l15) * 32 + (q8 ^ rsw8)];
        stageA(0, kt2, c);
        GQ_BARRIER();
        GQ_LGKM0();
        __builtin_amdgcn_s_setprio(1);
#pragma unroll
        for (int fm = 0; fm < 4; ++fm)
#pragma unroll
            for (int fn = 0; fn < 4; ++fn)
                acc[fm][fn] = __builtin_amdgcn_mfma_f32_16x16x32_bf16(a[fm], b[fn], acc[fm][fn], 0, 0, 0);
        __builtin_amdgcn_s_setprio(0);
        asm volatile("s_waitcnt vmcnt(2)" ::: "memory");
        GQ_BARRIER();
    }

    // ---- epilogue ----
#pragma unroll
    for (int fm = 0; fm < 4; ++fm)
#pragma unroll
        for (int r = 0; r < 4; ++r) {
            size_t base = (size_t)(m0 + wm0 + fm * 16 + quad * 4 + r) * N + n0 + wn0 + l15;
#pragma unroll
            for (int fn = 0; fn < 4; ++fn) {
                float v = acc[fm][fn][r];
                if (OUT_BF16) ((ushort*)Cv)[base + fn * 16] = f2bf(v);
                else          ((float*)Cv)[base + fn * 16] = v;
            }
        }
}

// ============================================================================
// Fused cast kernel (unchanged)
// ============================================================================
__global__ __launch_bounds__(256) void cast_all(
    const float* __restrict__ x, const float* __restrict__ wq,
    const float* __restrict__ wkva, const float* __restrict__ wkvb,
    const float* __restrict__ wo,
    ushort* __restrict__ xb, ushort* __restrict__ wc,
    ushort* __restrict__ wkvb_bf, ushort* __restrict__ wo_bf)
{
    size_t i = ((size_t)blockIdx.x * 256 + threadIdx.x) * 8;
    const float* s; ushort* d;
    if (i < 8388608)        { s = x + i;                  d = xb + i; }
    else if (i < 14680064)  { s = wq + (i - 8388608);     d = wc + (i - 8388608); }
    else if (i < 15859712)  { s = wkva + (i - 14680064);  d = wc + (i - 8388608); }
    else if (i < 16252928)  {
        ushort4 z = {0, 0, 0, 0};
        ushort* dz = wc + (i - 8388608);
        *(ushort4*)dz = z; *(ushort4*)(dz + 4) = z;
        return;
    }
    else if (i < 18350080)  { s = wkvb + (i - 16252928);  d = wkvb_bf + (i - 16252928); }
    else                    { s = wo + (i - 18350080);    d = wo_bf + (i - 18350080); }
    float4 a = *(const float4*)s;
    float4 b = *(const float4*)(s + 4);
    ushort4 o0, o1;
    o0.x = f2bf(a.x); o0.y = f2bf(a.y); o0.z = f2bf(a.z); o0.w = f2bf(a.w);
    o1.x = f2bf(b.x); o1.y = f2bf(b.y); o1.z = f2bf(b.z); o1.w = f2bf(b.w);
    *(ushort4*)d = o0;
    *(ushort4*)(d + 4) = o1;
}

// ============================================================================
// Fused RMSNorm + RoPE-k (unchanged, pitch 768)
// ============================================================================
__global__ __launch_bounds__(256) void rmsnorm_rope_k(
    const float* __restrict__ ckv, const float* __restrict__ nw,
    const float* __restrict__ rope_cache,
    ushort* __restrict__ cnorm, ushort* __restrict__ krb)
{
    const int lane = threadIdx.x & 63;
    const int row = blockIdx.x * 4 + (threadIdx.x >> 6);
    const float* src = ckv + (size_t)row * CKV_P_;
    float4 a = *(const float4*)(src + lane * 4);
    float4 b = *(const float4*)(src + 256 + lane * 4);
    float ss = a.x*a.x + a.y*a.y + a.z*a.z + a.w*a.w
             + b.x*b.x + b.y*b.y + b.z*b.z + b.w*b.w;
#pragma unroll
    for (int off = 32; off > 0; off >>= 1) ss += __shfl_xor(ss, off, 64);
    float rs = rsqrtf(ss * (1.0f / 512.0f) + EPS_);
    float4 w0 = *(const float4*)(nw + lane * 4);
    float4 w1 = *(const float4*)(nw + 256 + lane * 4);
    ushort* dst = cnorm + (size_t)row * KV_LORA_;
    ushort4 o0, o1;
    o0.x = f2bf(a.x*rs*w0.x); o0.y = f2bf(a.y*rs*w0.y);
    o0.z = f2bf(a.z*rs*w0.z); o0.w = f2bf(a.w*rs*w0.w);
    o1.x = f2bf(b.x*rs*w1.x); o1.y = f2bf(b.y*rs*w1.y);
    o1.z = f2bf(b.z*rs*w1.z); o1.w = f2bf(b.w*rs*w1.w);
    *(ushort4*)(dst + lane * 4) = o0;
    *(ushort4*)(dst + 256 + lane * 4) = o1;

    float v = src[KV_LORA_ + lane];
    float other = __shfl_xor(v, 32, 64);
    float rot = (lane < 32) ? -other : other;
    int s = row & (S_ - 1);
    float c  = rope_cache[s * (2 * ROPE_D_) + lane];
    float sn = rope_cache[s * (2 * ROPE_D_) + ROPE_D_ + lane];
    krb[(size_t)row * ROPE_D_ + lane] = f2bf(v * c + rot * sn);
}

// ============================================================================
// MFMA flash attention v9 = v8 with the register cap REVERTED to (512,2).
//  Round-10 lesson: __launch_bounds__(512,4) pinned the allocator to the
//  64-VGPR step -> ov[4] (64 regs) spilled -> 310 MB scratch traffic.
//  v7 compiled at 116 VGPR under (512,2); 116 <= 128 means the HW can still
//  co-schedule 2 blocks/CU (LDS 80KB x 2 = 160KB fits) — occupancy comes
//  from natural allocation, not a forced cap.
//  Keeps: grid 512 paired q-tiles (same bh, complementary qt per CU),
//  exp2-domain softmax, v_cvt_pk_bf16_f32 pack, coalesced swizzled staging.
// ============================================================================
__global__ __launch_bounds__(512, 2) void mla_attn_mfma9(
    const ushort* __restrict__ qb, const ushort* __restrict__ kvb,
    const ushort* __restrict__ krb, const ushort* __restrict__ vT,
    const float* __restrict__ rope_cache, ushort* __restrict__ attn)
{
    __shared__ __align__(16) ushort LDSU[40960];   // 80 KB
    const int KNo[2] = {0, 8192};
    const int KRo[2] = {16384, 20480};
    const int VVo[2] = {24576, 32768};

    const int tid = threadIdx.x;
    const int lane = tid & 63;
    const int w = tid >> 6;               // wave 0..7
    const int l31 = lane & 31, hi = lane >> 5;
    const int band = w & 3;               // 32-row q band
    const int koff = (w >> 2) * 32;       // k half of 64-row K tile

    // Pair mapping: lin and lin+256 -> same (xcd, cu) under round-robin
    // dispatch; same bh, complementary qt.  Bijective over (bh, qt).
    const int lin = (int)blockIdx.x;
    const int r256 = lin & 255, sl = lin >> 8;
    const int xcd = r256 & 7, cu = r256 >> 3;       // cu in [0,32)
    const int bh = xcd * 4 + (cu >> 3);             // 4 bh per XCD (L2-fit)
    const int jj = cu & 7;
    const int qt = sl ? (15 - jj) : jj;
    const int b = bh >> 4, h = bh & 15;
    const size_t bS = (size_t)b * S_;
    const float sc_l2e = 0.10411789f;     // 192^-0.5 * log2(e)

    auto stage = [&](int kbase, int bufi) {
        // K-nope: 64 rows x 16 chunks, 16 lanes/row
#pragma unroll
        for (int j = 0; j < 2; ++j) {
            int g = (j * 8 + w) * 64 + lane;
            int row = g >> 4;
            int d8 = (g & 15) ^ (row & 7);
            ushort* dst = &LDSU[KNo[bufi] + g * 8];
            const ushort* src = kvb + (bS + kbase + row) * 4096 + h * 256 + d8 * 8;
            gll16(src, dst);
        }
        // K-rope: 64 rows x 8 chunks, 8 lanes/row
        {
            int g = w * 64 + lane;
            int row = g >> 3;
            int r8 = (g & 7) ^ (row & 7);
            ushort* dst = &LDSU[KRo[bufi] + g * 8];
            const ushort* src = krb + (bS + kbase + row) * 64 + r8 * 8;
            gll16(src, dst);
        }
        // V: 128 vd-rows x 8 chunks, 8 lanes/row
#pragma unroll
        for (int j = 0; j < 2; ++j) {
            int g = (j * 8 + w) * 64 + lane;
            int vd = g >> 3;
            int kc = (g & 7) ^ (vd & 7);
            ushort* dst = &LDSU[VVo[bufi] + g * 8];
            const ushort* src = vT + ((size_t)bh * 128 + vd) * 2048 + kbase + kc * 8;
            gll16(src, dst);
        }
    };

    const int qbase = qt * 128;
    const int nkt = 2 * qt + 2;
    const int bmin = qbase + band * 32;   // wave's first q row

    stage(0, 0);

    // ---- Q fragments with fused RoPE on chunks 8..11 (cols 128..191) ----
    bf16x8 qf[12];
    {
        const ushort* qrow = qb + (bS + bmin + l31) * (size_t)(H_ * Q_D_) + h * Q_D_;
#pragma unroll
        for (int c = 0; c < 8; ++c)
            qf[c] = *(const bf16x8*)(qrow + c * 16 + hi * 8);
        bf16x8 q8  = *(const bf16x8*)(qrow + 128 + hi * 8);
        bf16x8 q9  = *(const bf16x8*)(qrow + 144 + hi * 8);
        bf16x8 q10 = *(const bf16x8*)(qrow + 160 + hi * 8);
        bf16x8 q11 = *(const bf16x8*)(qrow + 176 + hi * 8);
        const float* rc = rope_cache + (size_t)(bmin + l31) * 128 + hi * 8;
        f32x4 c8a = *(const f32x4*)(rc + 0),  c8b = *(const f32x4*)(rc + 4);
        f32x4 c9a = *(const f32x4*)(rc + 16), c9b = *(const f32x4*)(rc + 20);
        f32x4 cAa = *(const f32x4*)(rc + 32), cAb = *(const f32x4*)(rc + 36);
        f32x4 cBa = *(const f32x4*)(rc + 48), cBb = *(const f32x4*)(rc + 52);
        f32x4 s8a = *(const f32x4*)(rc + 64), s8b = *(const f32x4*)(rc + 68);
        f32x4 s9a = *(const f32x4*)(rc + 80), s9b = *(const f32x4*)(rc + 84);
        f32x4 sAa = *(const f32x4*)(rc + 96), sAb = *(const f32x4*)(rc + 100);
        f32x4 sBa = *(const f32x4*)(rc + 112), sBb = *(const f32x4*)(rc + 116);
        bf16x8 o8, o9, o10, o11;
#pragma unroll
        for (int e = 0; e < 4; ++e) {
            float a8 = bf2f((ushort)q8[e]),  b8 = bf2f((ushort)q8[e + 4]);
            float a9 = bf2f((ushort)q9[e]),  b9 = bf2f((ushort)q9[e + 4]);
            float aA = bf2f((ushort)q10[e]), bA = bf2f((ushort)q10[e + 4]);
            float aB = bf2f((ushort)q11[e]), bB = bf2f((ushort)q11[e + 4]);
            o8[e]      = (short)f2bf(a8 * c8a[e] - aA * s8a[e]);
            o8[e + 4]  = (short)f2bf(b8 * c8b[e] - bA * s8b[e]);
            o9[e]      = (short)f2bf(a9 * c9a[e] - aB * s9a[e]);
            o9[e + 4]  = (short)f2bf(b9 * c9b[e] - bB * s9b[e]);
            o10[e]     = (short)f2bf(aA * cAa[e] + a8 * sAa[e]);
            o10[e + 4] = (short)f2bf(bA * cAb[e] + b8 * sAb[e]);
            o11[e]     = (short)f2bf(aB * cBa[e] + a9 * sBa[e]);
            o11[e + 4] = (short)f2bf(bB * cBb[e] + b9 * sBb[e]);
        }
        qf[8] = o8; qf[9] = o9; qf[10] = o10; qf[11] = o11;
    }

    f32x16 ov[4];
#pragma unroll
    for (int vt = 0; vt < 4; ++vt)
#pragma unroll
        for (int r = 0; r < 16; ++r) ov[vt][r] = 0.f;
    float m_run = -3e38f, lsum = 0.f;     // m_run in log2 domain

    __syncthreads();                      // tile 0 visible

    const int krow = koff + l31;
    const int kx7 = krow & 7;
    const int vx7 = l31 & 7;

    for (int kt = 0; kt < nkt; ++kt) {
        const int kb = kt * 64;
        const int cur = kt & 1;
        if (kt + 1 < nkt) stage((kt + 1) * 64, cur ^ 1);

        const int kg = kb + koff;         // wave's 32-k strip start
        if (kg <= bmin + 31) {            // strip not fully masked
            f32x16 sc;
#pragma unroll
            for (int r = 0; r < 16; ++r) sc[r] = 0.f;
            __builtin_amdgcn_s_setprio(1);
#pragma unroll
            for (int c = 0; c < 12; ++c) {
                const bf16x8* kp;
                if (c < 8)
                    kp = (const bf16x8*)&LDSU[KNo[cur] + (krow * 16 + ((c * 2 + hi) ^ kx7)) * 8];
                else
                    kp = (const bf16x8*)&LDSU[KRo[cur] + (krow * 8 + (((c - 8) * 2 + hi) ^ kx7)) * 8];
                sc = __builtin_amdgcn_mfma_f32_32x32x16_bf16(*kp, qf[c], sc, 0, 0, 0);
            }
            __builtin_amdgcn_s_setprio(0);

            const bool need_mask = (kg == bmin);   // only diagonal strips
            float p[16]; float mx = -3e38f;
#pragma unroll
            for (int r = 0; r < 16; ++r) {
                float v = sc[r] * sc_l2e;          // log2-domain score
                if (need_mask) {
                    int kr = (r & 3) + 8 * (r >> 2) + 4 * hi;
                    if (kr > l31) v = -3e38f;
                }
                p[r] = v; mx = fmaxf(mx, v);
            }
            mx = fmaxf(mx, __shfl_xor(mx, 32, 64));   // full 64-k row max
            if (!__all(mx - m_run <= 11.5416f)) {     // 8 * log2(e)
                float mn = fmaxf(mx, m_run);
                float al;
                asm("v_exp_f32 %0, %1" : "=v"(al) : "v"(m_run - mn));  // 2^x
                m_run = mn; lsum *= al;
#pragma unroll
                for (int vt = 0; vt < 4; ++vt)
#pragma unroll
                    for (int r = 0; r < 16; ++r) ov[vt][r] *= al;
            }
            float s_loc = 0.f;
#pragma unroll
            for (int r = 0; r < 16; ++r) {
                float e;
                asm("v_exp_f32 %0, %1" : "=v"(e) : "v"(p[r] - m_run));  // 2^x
                p[r] = e; s_loc += e;
            }
            lsum += s_loc + __shfl_xor(s_loc, 32, 64);

            uint32_t w8[8];
#pragma unroll
            for (int m = 0; m < 8; ++m)
                asm("v_cvt_pk_bf16_f32 %0, %1, %2"
                    : "=v"(w8[m]) : "v"(p[2 * m]), "v"(p[2 * m + 1]));
            bf16x8 pb[2];
#pragma unroll
            for (int c = 0; c < 2; ++c) {
                uint32_t wd[4];
#pragma unroll
                for (int par = 0; par < 2; ++par) {
                    uint32_t a  = w8[4 * c + par];
                    uint32_t bb = w8[4 * c + 2 + par];
                    uint32_t t  = __shfl_xor(bb, 32, 64);
                    uint32_t t2 = __shfl_xor(a, 32, 64);
                    wd[par]     = hi ? t : a;
                    wd[par + 2] = hi ? bb : t2;
                }
                union { uint32_t u[4]; bf16x8 v; } cvt;
                cvt.u[0] = wd[0]; cvt.u[1] = wd[1]; cvt.u[2] = wd[2]; cvt.u[3] = wd[3];
                pb[c] = cvt.v;
            }

            __builtin_amdgcn_s_setprio(1);
#pragma unroll
            for (int vt = 0; vt < 4; ++vt)
#pragma unroll
                for (int cc = 0; cc < 2; ++cc) {
                    int vd = vt * 32 + l31;
                    int k8 = (koff >> 3) + cc * 2 + hi;
                    bf16x8 vf = *(const bf16x8*)
                        &LDSU[VVo[cur] + (vd * 8 + (k8 ^ vx7)) * 8];
                    ov[vt] = __builtin_amdgcn_mfma_f32_32x32x16_bf16(vf, pb[cc], ov[vt], 0, 0, 0);
                }
            __builtin_amdgcn_s_setprio(0);
        }
        __syncthreads();   // publish prefetched tile; WAR-protect buffers
    }

    float* mrg = (float*)LDSU;
    if (w >= 4) {
        float* dst = mrg + (size_t)((w - 4) * 64 + lane) * 68;
#pragma unroll
        for (int vt = 0; vt < 4; ++vt)
#pragma unroll
            for (int g = 0; g < 4; ++g) {
                f32x4 v4v = { ov[vt][g * 4 + 0], ov[vt][g * 4 + 1],
                              ov[vt][g * 4 + 2], ov[vt][g * 4 + 3] };
                *(f32x4*)(dst + vt * 16 + g * 4) = v4v;
            }
        dst[64] = m_run; dst[65] = lsum;
    }
    __syncthreads();
    if (w < 4) {
        const float* srcm = mrg + (size_t)(w * 64 + lane) * 68;
        float mB = srcm[64], lB = srcm[65];
        float M = fmaxf(m_run, mB);
        float eA, eB;
        asm("v_exp_f32 %0, %1" : "=v"(eA) : "v"(m_run - M));   // 2^x
        asm("v_exp_f32 %0, %1" : "=v"(eB) : "v"(mB - M));
        float L = lsum * eA + lB * eB;
        float inv = 1.0f / L;
        size_t obase = (bS + bmin + l31) * (size_t)(H_ * V_D_) + h * V_D_;
#pragma unroll
        for (int vt = 0; vt < 4; ++vt)
#pragma unroll
            for (int g = 0; g < 4; ++g) {
                ushort4 o;
                o.x = f2bf((ov[vt][g*4+0] * eA + srcm[vt*16+g*4+0] * eB) * inv);
                o.y = f2bf((ov[vt][g*4+1] * eA + srcm[vt*16+g*4+1] * eB) * inv);
                o.z = f2bf((ov[vt][g*4+2] * eA + srcm[vt*16+g*4+2] * eB) * inv);
                o.w = f2bf((ov[vt][g*4+3] * eA + srcm[vt*16+g*4+3] * eB) * inv);
                *(ushort4*)(attn + obase + vt * 32 + g * 8 + hi * 4) = o;
            }
    }
}

// ============================================================================
// launch — workspace ~138 MB (round-6..9 layout, unchanged)
// ============================================================================
extern "C" void kernel_launch(void* const* d_in, const int* in_sizes, int n_in,
                              void* d_out, int out_size, void* d_ws, size_t ws_size,
                              hipStream_t stream)
{
    const float* x          = (const float*)d_in[0];
    const float* rope_cache = (const float*)d_in[1];
    const float* wq         = (const float*)d_in[2];
    const float* wkva       = (const float*)d_in[3];
    const float* norm_w     = (const float*)d_in[4];
    const float* wkvb       = (const float*)d_in[5];
    const float* wo         = (const float*)d_in[6];
    float* out = (float*)d_out;

    char* p = (char*)d_ws;
    ushort* xb       = (ushort*)p; p += (size_t)BS_ * DIM_ * 2;        // 16.8 MB
    ushort* q_bf     = (ushort*)p; p += (size_t)BS_ * H_ * Q_D_ * 2;   // 25.2 MB
    float*  ckv      = (float*) p; p += (size_t)BS_ * CKV_P_ * 4;      // 12.6 MB
    ushort* cnorm_bf = (ushort*)p; p += (size_t)BS_ * KV_LORA_ * 2;    //  4.2 MB
    ushort* kvb      = (ushort*)p; p += (size_t)BS_ * 4096 * 2;        // 33.6 MB
    ushort* attn_bf  = (ushort*)p; p += (size_t)BS_ * 2048 * 2;        // 16.8 MB
    ushort* krb      = (ushort*)p; p += (size_t)BS_ * ROPE_D_ * 2;     //  0.5 MB
    ushort* wc_bf    = (ushort*)p; p += (size_t)3840 * DIM_ * 2;       // 15.7 MB
    ushort* wkvb_bf  = (ushort*)p; p += (size_t)4096 * KV_LORA_ * 2;   //  4.2 MB
    ushort* wo_bf    = (ushort*)p; p += (size_t)DIM_ * 2048 * 2;       //  8.4 MB
    ushort* vT       = xb;   // alias: xb dead after GEMM 1; same size

    // 0. all input casts in one dispatch
    cast_all<<<11008, dim3(256), 0, stream>>>(
        x, wq, wkva, wkvb, wo, xb, wc_bf, wkvb_bf, wo_bf);

    // 1. fused: q_bf = x @ wq^T (bf16) and ckv = x @ wkva^T (fp32, pitch 768)
    gemm256_8ph<2><<<dim3(16 * 15), dim3(512), 0, stream>>>(
        xb, wc_bf, q_bf, ckv, 0, DIM_, 15);
    // 2. cnorm + krb fused
    rmsnorm_rope_k<<<BS_ / 4, dim3(256), 0, stream>>>(
        ckv, norm_w, rope_cache, cnorm_bf, krb);
    // 3. kvb (K-nope) + vT (V transposed) = cnorm @ wkvb^T, fused epilogue
    gemm256_8ph<3><<<dim3(16 * 16), dim3(512), 0, stream>>>(
        cnorm_bf, wkvb_bf, kvb, vT, 4096, KV_LORA_, 16);
    // 4. flash attention v9 (grid 512, natural VGPR, paired q-tiles)
    mla_attn_mfma9<<<dim3(512), dim3(512), 0, stream>>>(
        q_bf, kvb, krb, vT, rope_cache, attn_bf);
    // 5. out = attn @ wo^T        (4096 x 2048 x 2048), fp32, 256 blocks
    gemm_bn128<0><<<dim3(16 * 16), dim3(512), 0, stream>>>(
        attn_bf, wo_bf, out, 2048, 2048, 16);
}